// Round 1
// 1361.905 us; speedup vs baseline: 1.0515x; 1.0515x over previous
//
#include <hip/hip_runtime.h>
#include <math.h>

#define HD 64   // H == F == 64
#define GD 50   // num gaussians
#define HALF 32 // half of HD: LDS row width (floats) for park + scatter passes

__device__ __forceinline__ float ssp_f(float x) {
    // shifted softplus: softplus(x) - ln2, stable form max(x,0)+log(1+exp(-|x|))
    float ax = __builtin_fabsf(x);
    float e  = __expf(-ax);
    float sp = fmaxf(x, 0.0f) + __logf(1.0f + e);
    return sp - 0.69314718055994531f;
}

// xs = x @ l1w : [N,64]; also zero agg (saves separate memset dispatches).
__global__ void __launch_bounds__(256) xs_kernel(const float* __restrict__ x,
                                                 const float* __restrict__ w,
                                                 float* __restrict__ xs,
                                                 float* __restrict__ agg, int N) {
    int wv = threadIdx.x >> 6;
    int j  = threadIdx.x & 63;
    int n  = blockIdx.x * 4 + wv;
    __shared__ float xr[4][64];
    if (n < N) xr[wv][j] = x[(size_t)n * HD + j];
    __syncthreads();
    if (n >= N) return;
    float acc = 0.0f;
#pragma unroll
    for (int k = 0; k < HD; ++k)
        acc = fmaf(xr[wv][k], w[k * HD + j], acc);
    xs[(size_t)n * HD + j] = acc;
    agg[(size_t)n * HD + j] = 0.0f;
}

// Per-edge filter MLP + modulate + scatter.
//   Occupancy redesign vs previous version: LDS per wave halved (16KB -> 8.5KB)
//   so blocks/CU goes 4 -> 9; VGPR capped at 128 via launch_bounds(128,4)
//   -> 16 waves/CU (was 8).
//   Layer 1: h[64] in VGPRs. Park only h[32..64) in LDS (32 floats/edge).
//   Layer 2 part A: consume ssp(h[0..31]) straight from registers
//   (fully unrolled -> static indexing, no scratch). Part B: read parked
//   upper half back from LDS in float4 blocks (runtime loop).
//   Scatter: two 32-channel passes; the same 8KB LDS row holds w_lo*cw then
//   w_hi*cw (transposed read). Lane -> channel (lane&31); half-wave selects
//   edge t vs t+32 (2-way LDS bank aliasing = free).
#define EPW 64
#define WPB 2
__global__ void __launch_bounds__(WPB * 64, 4) edge_kernel(
        const float* __restrict__ ea, const float* __restrict__ ew,
        const int* __restrict__ ei, const float* __restrict__ xs,
        float* __restrict__ agg,
        const float* __restrict__ mw1, const float* __restrict__ mb1,
        const float* __restrict__ mw2, const float* __restrict__ mb2,
        int E) {
    const int wv   = threadIdx.x >> 6;
    const int lane = threadIdx.x & 63;
    const long ebase = ((long)blockIdx.x * WPB + wv) * EPW;

    __shared__ float wbuf[WPB][EPW * HALF];  // 2*64*32*4 = 16 KB: h_hi park, then w halves
    __shared__ int   sdst[WPB][EPW];
    __shared__ int   ssrc[WPB][EPW];

    long e = ebase + lane;
    bool valid = e < (long)E;
    long ec = valid ? e : (long)E - 1;

    // ---- layer 1: h = ea_row @ mw1 + mb1 (h static-indexed -> VGPRs) ----
    const float2* ear2 = (const float2*)(ea + ec * GD);
    float h[HD];
#pragma unroll
    for (int f = 0; f < HD; ++f) h[f] = mb1[f];
    for (int gc = 0; gc < GD / 2; ++gc) {       // 25 iters, uniform weight rows
        float2 v = ear2[gc];
        const float* wr = mw1 + 2 * gc * HD;
#pragma unroll
        for (int f = 0; f < HD; ++f) h[f] = fmaf(v.x, wr[f], h[f]);
#pragma unroll
        for (int f = 0; f < HD; ++f) h[f] = fmaf(v.y, wr[HD + f], h[f]);
    }

    // ---- park upper half of h (raw) in own LDS row: 32 floats, b128 stores ----
    float* hrow = &wbuf[wv][lane * HALF];
#pragma unroll
    for (int q = 0; q < HALF / 4; ++q)
        *(float4*)(hrow + 4 * q) = make_float4(h[HALF + 4*q],     h[HALF + 4*q + 1],
                                               h[HALF + 4*q + 2], h[HALF + 4*q + 3]);

    float w[HD];
#pragma unroll
    for (int j = 0; j < HD; ++j) w[j] = mb2[j];

    // ---- layer 2 part A: g in [0,32) from registers (fully unrolled) ----
#pragma unroll
    for (int gb = 0; gb < HALF / 4; ++gb) {
        float s0 = ssp_f(h[4*gb + 0]);
        float s1 = ssp_f(h[4*gb + 1]);
        float s2 = ssp_f(h[4*gb + 2]);
        float s3 = ssp_f(h[4*gb + 3]);
        const float* wr = mw2 + 4 * gb * HD;
#pragma unroll
        for (int j = 0; j < HD; ++j) w[j] = fmaf(s0, wr[j], w[j]);
#pragma unroll
        for (int j = 0; j < HD; ++j) w[j] = fmaf(s1, wr[HD + j], w[j]);
#pragma unroll
        for (int j = 0; j < HD; ++j) w[j] = fmaf(s2, wr[2 * HD + j], w[j]);
#pragma unroll
        for (int j = 0; j < HD; ++j) w[j] = fmaf(s3, wr[3 * HD + j], w[j]);
    }

    // ---- layer 2 part B: g in [32,64) from LDS (runtime loop, b128 reads) ----
    for (int gb = 0; gb < HALF / 4; ++gb) {
        float4 hv = *(const float4*)(hrow + 4 * gb);
        float s0 = ssp_f(hv.x), s1 = ssp_f(hv.y), s2 = ssp_f(hv.z), s3 = ssp_f(hv.w);
        const float* wr = mw2 + (HALF + 4 * gb) * HD;
#pragma unroll
        for (int j = 0; j < HD; ++j) w[j] = fmaf(s0, wr[j], w[j]);
#pragma unroll
        for (int j = 0; j < HD; ++j) w[j] = fmaf(s1, wr[HD + j], w[j]);
#pragma unroll
        for (int j = 0; j < HD; ++j) w[j] = fmaf(s2, wr[2 * HD + j], w[j]);
#pragma unroll
        for (int j = 0; j < HD; ++j) w[j] = fmaf(s3, wr[3 * HD + j], w[j]);
    }

    // fold cosine cutoff; zero invalid edges so their atomics are no-ops
    float cw = 0.5f * (__cosf(ew[ec] * 0.31415926535897931f) + 1.0f);
    if (!valid) cw = 0.0f;

    sdst[wv][lane] = ei[(size_t)E + ec];
    ssrc[wv][lane] = ei[ec];

    const int c  = lane & 31;   // channel within half
    const int eh = lane & 32;   // which edge half this lane handles

    // ---- pass 0: channels [0,32) ----
#pragma unroll
    for (int q = 0; q < HALF / 4; ++q)
        *(float4*)(hrow + 4 * q) = make_float4(w[4*q] * cw,     w[4*q + 1] * cw,
                                               w[4*q + 2] * cw, w[4*q + 3] * cw);
    __syncthreads();
#pragma unroll 8
    for (int t = 0; t < EPW / 2; ++t) {
        int idx = t + eh;
        int dst = sdst[wv][idx];
        int src = ssrc[wv][idx];
        float m = xs[(size_t)src * HD + c] * wbuf[wv][idx * HALF + c];
        atomicAdd(&agg[(size_t)dst * HD + c], m);
    }
    __syncthreads();   // all lanes done reading before overwrite

    // ---- pass 1: channels [32,64) ----
#pragma unroll
    for (int q = 0; q < HALF / 4; ++q)
        *(float4*)(hrow + 4 * q) = make_float4(w[HALF + 4*q] * cw,     w[HALF + 4*q + 1] * cw,
                                               w[HALF + 4*q + 2] * cw, w[HALF + 4*q + 3] * cw);
    __syncthreads();
#pragma unroll 8
    for (int t = 0; t < EPW / 2; ++t) {
        int idx = t + eh;
        int dst = sdst[wv][idx];
        int src = ssrc[wv][idx];
        float m = xs[(size_t)src * HD + HALF + c] * wbuf[wv][idx * HALF + c];
        atomicAdd(&agg[(size_t)dst * HD + HALF + c], m);
    }
}

// out = ssp(agg @ l2w + l2b) @ lin_w + lin_b. One wave per node, LDS broadcast.
__global__ void __launch_bounds__(256) out_kernel(
        const float* __restrict__ agg,
        const float* __restrict__ l2w, const float* __restrict__ l2b,
        const float* __restrict__ lw, const float* __restrict__ lb,
        float* __restrict__ out, int N) {
    int wv = threadIdx.x >> 6;
    int j  = threadIdx.x & 63;
    int n  = blockIdx.x * 4 + wv;
    __shared__ float buf[4][64];
    bool ok = n < N;
    if (ok) buf[wv][j] = agg[(size_t)n * HD + j];
    __syncthreads();
    float h = l2b[j];
#pragma unroll
    for (int g = 0; g < HD; ++g)
        h = fmaf(buf[wv][g], l2w[g * HD + j], h);
    h = ssp_f(h);
    __syncthreads();
    buf[wv][j] = h;
    __syncthreads();
    float o = lb[j];
#pragma unroll
    for (int g = 0; g < HD; ++g)
        o = fmaf(buf[wv][g], lw[g * HD + j], o);
    if (ok) out[(size_t)n * HD + j] = o;
}

extern "C" void kernel_launch(void* const* d_in, const int* in_sizes, int n_in,
                              void* d_out, int out_size, void* d_ws, size_t ws_size,
                              hipStream_t stream) {
    const float* x0   = (const float*)d_in[0];
    const float* x1   = (const float*)d_in[1];
    const int*   ei0  = (const int*)d_in[2];
    const int*   ei1  = (const int*)d_in[3];
    const float* ew0  = (const float*)d_in[4];
    const float* ew1  = (const float*)d_in[5];
    const float* ea0  = (const float*)d_in[6];
    const float* ea1  = (const float*)d_in[7];
    const float* mw1  = (const float*)d_in[8];
    const float* mb1  = (const float*)d_in[9];
    const float* mw2  = (const float*)d_in[10];
    const float* mb2  = (const float*)d_in[11];
    const float* l1w0 = (const float*)d_in[12];
    const float* l2w0 = (const float*)d_in[13];
    const float* l2b0 = (const float*)d_in[14];
    const float* l1w1 = (const float*)d_in[15];
    const float* l2w1 = (const float*)d_in[16];
    const float* l2b1 = (const float*)d_in[17];
    const float* lw   = (const float*)d_in[18];
    const float* lb   = (const float*)d_in[19];

    int N = in_sizes[0] / HD;
    int E = in_sizes[4];
    float* out = (float*)d_out;

    float* xs  = (float*)d_ws;
    float* agg = xs + (size_t)N * HD;

    int nodeBlocks = (N + 3) / 4;
    int edgeBlocks = (E + WPB * EPW - 1) / (WPB * EPW);

    for (int t = 0; t < 2; ++t) {
        const float* x   = t ? x1 : x0;
        const int*   ei  = t ? ei1 : ei0;
        const float* ew  = t ? ew1 : ew0;
        const float* ea  = t ? ea1 : ea0;
        const float* l1w = t ? l1w1 : l1w0;
        const float* l2w = t ? l2w1 : l2w0;
        const float* l2b = t ? l2b1 : l2b0;
        float* outp = out + (size_t)t * (size_t)N * HD;

        xs_kernel<<<nodeBlocks, 256, 0, stream>>>(x, l1w, xs, agg, N);
        edge_kernel<<<edgeBlocks, WPB * 64, 0, stream>>>(ea, ew, ei, xs, agg,
                                                         mw1, mb1, mw2, mb2, E);
        out_kernel<<<nodeBlocks, 256, 0, stream>>>(agg, l2w, l2b, lw, lb, outp, N);
    }
}

// Round 2
// 1256.161 us; speedup vs baseline: 1.1400x; 1.0842x over previous
//
#include <hip/hip_runtime.h>
#include <math.h>

#define HD 64   // H == F == 64
#define GD 50   // num gaussians
#define HALF 32 // half of HD: LDS row width (floats) for park + scatter passes
#define PAD 36  // LDS row stride in floats: 144B, 16B-aligned, mod32==4 -> b128 spread over all 8 bank groups

__device__ __forceinline__ float ssp_f(float x) {
    // shifted softplus: softplus(x) - ln2, stable form max(x,0)+log(1+exp(-|x|))
    float ax = __builtin_fabsf(x);
    float e  = __expf(-ax);
    float sp = fmaxf(x, 0.0f) + __logf(1.0f + e);
    return sp - 0.69314718055994531f;
}

// xs = x @ l1w : [N,64]; also zero agg (saves separate memset dispatches).
__global__ void __launch_bounds__(256) xs_kernel(const float* __restrict__ x,
                                                 const float* __restrict__ w,
                                                 float* __restrict__ xs,
                                                 float* __restrict__ agg, int N) {
    int wv = threadIdx.x >> 6;
    int j  = threadIdx.x & 63;
    int n  = blockIdx.x * 4 + wv;
    __shared__ float xr[4][64];
    if (n < N) xr[wv][j] = x[(size_t)n * HD + j];
    __syncthreads();
    if (n >= N) return;
    float acc = 0.0f;
#pragma unroll
    for (int k = 0; k < HD; ++k)
        acc = fmaf(xr[wv][k], w[k * HD + j], acc);
    xs[(size_t)n * HD + j] = acc;
    agg[(size_t)n * HD + j] = 0.0f;
}

// Per-edge filter MLP + modulate + scatter.
//   LDS halved vs the 68-pad version (8 blocks/CU, 16 waves) but with the
//   conflict-free stride restored: PAD=36 (mod 32 == 4, same spread as 68).
//   Layer 1: h[64] in VGPRs, ea loads register-double-buffered.
//   Park h[32..64) in LDS; layer-2 part A consumes ssp(h[0..31]) from regs
//   (fully unrolled), part B reads the parked half back via b128 (prefetched).
//   Scatter: two 32-channel passes over the same 9KB LDS row. Pass 0 loads the
//   FULL xs row (both halves) per edge and stashes the upper half in 32
//   statically-indexed VGPRs; pass 1 does zero global reads. This keeps each
//   xs row's 4 cache lines touched back-to-back (L2-friendly).
#define EPW 64
#define WPB 2
__global__ void __launch_bounds__(WPB * 64, 4) edge_kernel(
        const float* __restrict__ ea, const float* __restrict__ ew,
        const int* __restrict__ ei, const float* __restrict__ xs,
        float* __restrict__ agg,
        const float* __restrict__ mw1, const float* __restrict__ mb1,
        const float* __restrict__ mw2, const float* __restrict__ mb2,
        int E) {
    const int wv   = threadIdx.x >> 6;
    const int lane = threadIdx.x & 63;
    const long ebase = ((long)blockIdx.x * WPB + wv) * EPW;

    __shared__ float wbuf[WPB][EPW * PAD];  // 18432 B: h_hi park, then w halves
    __shared__ int   sdst[WPB][EPW];
    __shared__ int   ssrc[WPB][EPW];

    long e = ebase + lane;
    bool valid = e < (long)E;
    long ec = valid ? e : (long)E - 1;

    // ---- layer 1: h = ea_row @ mw1 + mb1 (h static-indexed -> VGPRs) ----
    const float2* ear2 = (const float2*)(ea + ec * GD);
    float h[HD];
#pragma unroll
    for (int f = 0; f < HD; ++f) h[f] = mb1[f];
    {
        float2 v = ear2[0];
        for (int gc = 0; gc < GD / 2; ++gc) {   // 25 iters; next load hidden under FMAs
            int gn = gc + 1 < GD / 2 ? gc + 1 : GD / 2 - 1;
            float2 vn = ear2[gn];
            const float* wr = mw1 + 2 * gc * HD;
#pragma unroll
            for (int f = 0; f < HD; ++f) h[f] = fmaf(v.x, wr[f], h[f]);
#pragma unroll
            for (int f = 0; f < HD; ++f) h[f] = fmaf(v.y, wr[HD + f], h[f]);
            v = vn;
        }
    }

    // ---- park upper half of h (raw) in own LDS row: 32 floats, b128 stores ----
    float* hrow = &wbuf[wv][lane * PAD];
#pragma unroll
    for (int q = 0; q < HALF / 4; ++q)
        *(float4*)(hrow + 4 * q) = make_float4(h[HALF + 4*q],     h[HALF + 4*q + 1],
                                               h[HALF + 4*q + 2], h[HALF + 4*q + 3]);

    float w[HD];
#pragma unroll
    for (int j = 0; j < HD; ++j) w[j] = mb2[j];

    // ---- layer 2 part A: g in [0,32) from registers (fully unrolled) ----
#pragma unroll
    for (int gb = 0; gb < HALF / 4; ++gb) {
        float s0 = ssp_f(h[4*gb + 0]);
        float s1 = ssp_f(h[4*gb + 1]);
        float s2 = ssp_f(h[4*gb + 2]);
        float s3 = ssp_f(h[4*gb + 3]);
        const float* wr = mw2 + 4 * gb * HD;
#pragma unroll
        for (int j = 0; j < HD; ++j) w[j] = fmaf(s0, wr[j], w[j]);
#pragma unroll
        for (int j = 0; j < HD; ++j) w[j] = fmaf(s1, wr[HD + j], w[j]);
#pragma unroll
        for (int j = 0; j < HD; ++j) w[j] = fmaf(s2, wr[2 * HD + j], w[j]);
#pragma unroll
        for (int j = 0; j < HD; ++j) w[j] = fmaf(s3, wr[3 * HD + j], w[j]);
    }

    // ---- layer 2 part B: g in [32,64) from LDS (prefetched b128 reads) ----
    {
        float4 hv = *(const float4*)(hrow);
        for (int gb = 0; gb < HALF / 4; ++gb) {
            int gn = gb + 1 < HALF / 4 ? gb + 1 : HALF / 4 - 1;
            float4 hn = *(const float4*)(hrow + 4 * gn);
            float s0 = ssp_f(hv.x), s1 = ssp_f(hv.y), s2 = ssp_f(hv.z), s3 = ssp_f(hv.w);
            const float* wr = mw2 + (HALF + 4 * gb) * HD;
#pragma unroll
            for (int j = 0; j < HD; ++j) w[j] = fmaf(s0, wr[j], w[j]);
#pragma unroll
            for (int j = 0; j < HD; ++j) w[j] = fmaf(s1, wr[HD + j], w[j]);
#pragma unroll
            for (int j = 0; j < HD; ++j) w[j] = fmaf(s2, wr[2 * HD + j], w[j]);
#pragma unroll
            for (int j = 0; j < HD; ++j) w[j] = fmaf(s3, wr[3 * HD + j], w[j]);
            hv = hn;
        }
    }

    // fold cosine cutoff; zero invalid edges so their atomics are no-ops
    float cw = 0.5f * (__cosf(ew[ec] * 0.31415926535897931f) + 1.0f);
    if (!valid) cw = 0.0f;

    sdst[wv][lane] = ei[(size_t)E + ec];
    ssrc[wv][lane] = ei[ec];

    const int c  = lane & 31;   // channel within half
    const int eh = lane & 32;   // which edge half this lane handles

    // ---- pass 0: channels [0,32); also load + stash the upper xs half ----
#pragma unroll
    for (int q = 0; q < HALF / 4; ++q)
        *(float4*)(hrow + 4 * q) = make_float4(w[4*q] * cw,     w[4*q + 1] * cw,
                                               w[4*q + 2] * cw, w[4*q + 3] * cw);
    __syncthreads();
    float xh[EPW / 2];   // statically indexed (full unroll) -> stays in VGPRs
#pragma unroll
    for (int t = 0; t < EPW / 2; ++t) {
        int idx = t + eh;
        int dst = sdst[wv][idx];
        int src = ssrc[wv][idx];
        const float* xp = xs + (size_t)src * HD + c;
        float xlo = xp[0];
        xh[t] = xp[HALF];
        float m = xlo * wbuf[wv][idx * PAD + c];
        atomicAdd(&agg[(size_t)dst * HD + c], m);
    }
    __syncthreads();   // all lanes done reading before overwrite

    // ---- pass 1: channels [32,64); zero global reads ----
#pragma unroll
    for (int q = 0; q < HALF / 4; ++q)
        *(float4*)(hrow + 4 * q) = make_float4(w[HALF + 4*q] * cw,     w[HALF + 4*q + 1] * cw,
                                               w[HALF + 4*q + 2] * cw, w[HALF + 4*q + 3] * cw);
    __syncthreads();
#pragma unroll
    for (int t = 0; t < EPW / 2; ++t) {
        int idx = t + eh;
        int dst = sdst[wv][idx];
        float m = xh[t] * wbuf[wv][idx * PAD + c];
        atomicAdd(&agg[(size_t)dst * HD + HALF + c], m);
    }
}

// out = ssp(agg @ l2w + l2b) @ lin_w + lin_b. One wave per node, LDS broadcast.
__global__ void __launch_bounds__(256) out_kernel(
        const float* __restrict__ agg,
        const float* __restrict__ l2w, const float* __restrict__ l2b,
        const float* __restrict__ lw, const float* __restrict__ lb,
        float* __restrict__ out, int N) {
    int wv = threadIdx.x >> 6;
    int j  = threadIdx.x & 63;
    int n  = blockIdx.x * 4 + wv;
    __shared__ float buf[4][64];
    bool ok = n < N;
    if (ok) buf[wv][j] = agg[(size_t)n * HD + j];
    __syncthreads();
    float h = l2b[j];
#pragma unroll
    for (int g = 0; g < HD; ++g)
        h = fmaf(buf[wv][g], l2w[g * HD + j], h);
    h = ssp_f(h);
    __syncthreads();
    buf[wv][j] = h;
    __syncthreads();
    float o = lb[j];
#pragma unroll
    for (int g = 0; g < HD; ++g)
        o = fmaf(buf[wv][g], lw[g * HD + j], o);
    if (ok) out[(size_t)n * HD + j] = o;
}

extern "C" void kernel_launch(void* const* d_in, const int* in_sizes, int n_in,
                              void* d_out, int out_size, void* d_ws, size_t ws_size,
                              hipStream_t stream) {
    const float* x0   = (const float*)d_in[0];
    const float* x1   = (const float*)d_in[1];
    const int*   ei0  = (const int*)d_in[2];
    const int*   ei1  = (const int*)d_in[3];
    const float* ew0  = (const float*)d_in[4];
    const float* ew1  = (const float*)d_in[5];
    const float* ea0  = (const float*)d_in[6];
    const float* ea1  = (const float*)d_in[7];
    const float* mw1  = (const float*)d_in[8];
    const float* mb1  = (const float*)d_in[9];
    const float* mw2  = (const float*)d_in[10];
    const float* mb2  = (const float*)d_in[11];
    const float* l1w0 = (const float*)d_in[12];
    const float* l2w0 = (const float*)d_in[13];
    const float* l2b0 = (const float*)d_in[14];
    const float* l1w1 = (const float*)d_in[15];
    const float* l2w1 = (const float*)d_in[16];
    const float* l2b1 = (const float*)d_in[17];
    const float* lw   = (const float*)d_in[18];
    const float* lb   = (const float*)d_in[19];

    int N = in_sizes[0] / HD;
    int E = in_sizes[4];
    float* out = (float*)d_out;

    float* xs  = (float*)d_ws;
    float* agg = xs + (size_t)N * HD;

    int nodeBlocks = (N + 3) / 4;
    int edgeBlocks = (E + WPB * EPW - 1) / (WPB * EPW);

    for (int t = 0; t < 2; ++t) {
        const float* x   = t ? x1 : x0;
        const int*   ei  = t ? ei1 : ei0;
        const float* ew  = t ? ew1 : ew0;
        const float* ea  = t ? ea1 : ea0;
        const float* l1w = t ? l1w1 : l1w0;
        const float* l2w = t ? l2w1 : l2w0;
        const float* l2b = t ? l2b1 : l2b0;
        float* outp = out + (size_t)t * (size_t)N * HD;

        xs_kernel<<<nodeBlocks, 256, 0, stream>>>(x, l1w, xs, agg, N);
        edge_kernel<<<edgeBlocks, WPB * 64, 0, stream>>>(ea, ew, ei, xs, agg,
                                                         mw1, mb1, mw2, mb2, E);
        out_kernel<<<nodeBlocks, 256, 0, stream>>>(agg, l2w, l2b, lw, lb, outp, N);
    }
}